// Round 13
// baseline (922.574 us; speedup 1.0000x reference)
//
#include <hip/hip_runtime.h>

typedef _Float16 half_t;
typedef _Float16 f16x8 __attribute__((ext_vector_type(8)));
typedef _Float16 f16x4 __attribute__((ext_vector_type(4)));
typedef float f32x4 __attribute__((ext_vector_type(4)));

#define D_MODEL 1024
#define BS 4
#define SEQ 4096
#define ROWS (BS * SEQ)   // 16384
#define SC 32
#define NC (SEQ / SC)     // 128

#define BARRIER() asm volatile("s_barrier" ::: "memory")
#define WAITV(n)  asm volatile("s_waitcnt vmcnt(" #n ")" ::: "memory")

__device__ __forceinline__ void gld_lds16(const half_t* g, char* l) {
  __builtin_amdgcn_global_load_lds((const __attribute__((address_space(1))) void*)g,
                                   (__attribute__((address_space(3))) void*)l, 16, 0, 0);
}

// ================= setup1: ln + prep_w + detect_nz + copy_bias (fused) =================
__global__ __launch_bounds__(256) void setup1(const float* __restrict__ x,
                                              const float* __restrict__ gamma,
                                              const float* __restrict__ beta,
                                              half_t* __restrict__ h,
                                              const float* __restrict__ Wq,
                                              const float* __restrict__ Wk,
                                              const float* __restrict__ Wv,
                                              const float* __restrict__ Wqa,
                                              const float* __restrict__ Wka,
                                              half_t* __restrict__ wcat,
                                              half_t* __restrict__ wqa,
                                              half_t* __restrict__ wka,
                                              const float* __restrict__ bq,
                                              const float* __restrict__ bk,
                                              const float* __restrict__ bv,
                                              float* __restrict__ bcat,
                                              unsigned* __restrict__ nzpart) {
  __shared__ float sh[33 * 32];
  const int b = blockIdx.x;
  const int t = threadIdx.x;
  if (b < 16384) {
    // ---- layernorm row b (x is single-read: non-temporal) ----
    const float* xr = x + (size_t)b * D_MODEL + t * 4;
    f32x4 v = __builtin_nontemporal_load((const f32x4*)xr);
    float s = v[0] + v[1] + v[2] + v[3];
    float q = v[0]*v[0] + v[1]*v[1] + v[2]*v[2] + v[3]*v[3];
#pragma unroll
    for (int off = 32; off > 0; off >>= 1) {
      s += __shfl_down(s, off, 64);
      q += __shfl_down(q, off, 64);
    }
    const int wv = t >> 6, ln = t & 63;
    if (ln == 0) { sh[wv] = s; sh[4 + wv] = q; }
    __syncthreads();
    s = sh[0] + sh[1] + sh[2] + sh[3];
    q = sh[4] + sh[5] + sh[6] + sh[7];
    const float mu = s * (1.0f / D_MODEL);
    const float var = q * (1.0f / D_MODEL) - mu * mu;
    const float rstd = rsqrtf(var + 1e-5f);
    f32x4 g = *(const f32x4*)(gamma + t * 4);
    f32x4 bb = *(const f32x4*)(beta + t * 4);
    f16x4 o;
#pragma unroll
    for (int i = 0; i < 4; i++) o[i] = (half_t)((v[i] - mu) * rstd * g[i] + bb[i]);
    *(f16x4*)(h + (size_t)b * D_MODEL + t * 4) = o;
  } else if (b < 21504) {
    const int bi = b - 16384;
    const int mat = bi >> 10;
    const int tile = bi & 1023;
    const int tn = (tile & 31) * 32;
    const int tk = (tile >> 5) * 32;
    const float* W = mat == 0 ? Wq : mat == 1 ? Wk : mat == 2 ? Wv : mat == 3 ? Wqa : Wka;
    half_t* dst = mat < 3 ? wcat + (size_t)mat * D_MODEL * D_MODEL : (mat == 3 ? wqa : wka);
    float (*tl)[33] = (float(*)[33])sh;
    const int tx = t & 31, ty = t >> 5;
#pragma unroll
    for (int i = 0; i < 32; i += 8)
      tl[ty + i][tx] = W[(size_t)(tk + ty + i) * D_MODEL + tn + tx];
    __syncthreads();
#pragma unroll
    for (int i = 0; i < 32; i += 8)
      dst[(size_t)(tn + ty + i) * D_MODEL + tk + tx] = (half_t)tl[tx][ty + i];
  } else if (b < 22016) {
    const int bi = b - 21504;
    const int which = bi >> 8;
    const unsigned* w = (const unsigned*)(which ? Wka : Wqa);
    const int blk = bi & 255;
    unsigned v = 0;
    const size_t base = (size_t)blk * 4096 + t;
#pragma unroll
    for (int i = 0; i < 16; ++i) v |= w[base + i * 256];
#pragma unroll
    for (int off = 32; off > 0; off >>= 1) v |= __shfl_down(v, off, 64);
    unsigned* sv = (unsigned*)sh;
    if ((t & 63) == 0) sv[t >> 6] = v;
    __syncthreads();
    if (t == 0) nzpart[bi] = sv[0] | sv[1] | sv[2] | sv[3];
  } else {
    const int i = (b - 22016) * 256 + t;
    if (i < 1024) bcat[i] = bq[i];
    else if (i < 2048) bcat[i] = bk[i - 1024];
    else if (i < 3072) bcat[i] = bv[i - 2048];
  }
}

// ================= setup2: flag reduce + bias softmax (2 blocks) =================
__global__ __launch_bounds__(256) void setup2(const unsigned* __restrict__ nzpart,
                                              int* __restrict__ flags,
                                              const float* __restrict__ bqa,
                                              const float* __restrict__ bka,
                                              float* __restrict__ qwv,
                                              float* __restrict__ kwv) {
  const int b = blockIdx.x;
  const int t = threadIdx.x;
  __shared__ float sm[4], ssum[4];
  __shared__ unsigned su[4];
  unsigned u = nzpart[b * 256 + t];
#pragma unroll
  for (int off = 32; off > 0; off >>= 1) u |= __shfl_down(u, off, 64);
  const int wv = t >> 6, ln = t & 63;
  if (ln == 0) su[wv] = u;
  __syncthreads();
  if (t == 0) flags[b] = (su[0] | su[1] | su[2] | su[3]) ? 1 : 0;
  const float* bb = b ? bka : bqa;
  float* o = b ? kwv : qwv;
  f32x4 v = *(const f32x4*)(bb + t * 4);
  float xv[4];
#pragma unroll
  for (int i = 0; i < 4; i++) xv[i] = v[i] * 0.03125f;
  float mx = fmaxf(fmaxf(xv[0], xv[1]), fmaxf(xv[2], xv[3]));
#pragma unroll
  for (int off = 32; off > 0; off >>= 1) mx = fmaxf(mx, __shfl_xor(mx, off, 64));
  if (ln == 0) sm[wv] = mx;
  __syncthreads();
  mx = fmaxf(fmaxf(sm[0], sm[1]), fmaxf(sm[2], sm[3]));
  float e[4]; float s = 0.f;
#pragma unroll
  for (int i = 0; i < 4; i++) { e[i] = expf(xv[i] - mx); s += e[i]; }
#pragma unroll
  for (int off = 32; off > 0; off >>= 1) s += __shfl_xor(s, off, 64);
  if (ln == 0) ssum[wv] = s;
  __syncthreads();
  s = ssum[0] + ssum[1] + ssum[2] + ssum[3];
  const float r = 1.0f / s;
  f32x4 ov;
#pragma unroll
  for (int i = 0; i < 4; i++) ov[i] = e[i] * r;
  *(f32x4*)(o + t * 4) = ov;
}

// ================= 256x256 MFMA GEMM (16x16x32), K=1024, SINGLE 64KB buffer =================
// In-place region staging: after P1, regions Aα/Bγ/Bδ of tile kt are dead (all
// read in P1); Aβ dies after P3. Stage kt+1: {Aα,Bγ}@P2, Bδ@P3, Aβ@P4.
// Counted waits: WAITV(4)@P2-end (drains Aβ(kt) before P3 reads), WAITV(2)@P4-end
// (drains kt+1's Aα/Bγ/Bδ before next P1). 64KB LDS -> 2 blocks/CU, 4 waves/SIMD.

#define SA2(rb, kt) do { \
  gld_lds16(gA + (size_t)((rb) + wbA + r8) * lda + (size_t)(kt) * 64 + grn * 8, \
            smem + ((rb) + wbA) * 128); \
  gld_lds16(gA + (size_t)((rb) + 128 + wbA + r8) * lda + (size_t)(kt) * 64 + grn * 8, \
            smem + ((rb) + 128 + wbA) * 128); \
} while (0)

#define SB2(gd, kt) do { \
  gld_lds16(gB + (size_t)((gd) + wbB + r8) * 1024 + (size_t)(kt) * 64 + grn * 8, \
            smem + 32768 + ((gd) + wbB) * 128); \
  gld_lds16(gB + (size_t)((gd) + 128 + wbB + r8) * 1024 + (size_t)(kt) * 64 + grn * 8, \
            smem + 32768 + ((gd) + 128 + wbB) * 128); \
} while (0)

#define LOAD_A(base) do { \
  _Pragma("unroll") for (int _fm = 0; _fm < 4; ++_fm) { \
    aF[_fm][0] = *(const f16x8*)(smem + rA + gsw0 + ((base)+_fm)*2048); \
    aF[_fm][1] = *(const f16x8*)(smem + rA + gsw1 + ((base)+_fm)*2048); \
  } \
} while (0)

#define LOAD_B(dst, base) do { \
  _Pragma("unroll") for (int _fn = 0; _fn < 2; ++_fn) { \
    dst[_fn][0] = *(const f16x8*)(smem + 32768 + rB + gsw0 + ((base)+_fn)*2048); \
    dst[_fn][1] = *(const f16x8*)(smem + 32768 + rB + gsw1 + ((base)+_fn)*2048); \
  } \
} while (0)

#define QUAD(BR, MOFF, NOFF) do { \
  __builtin_amdgcn_s_setprio(1); \
  _Pragma("unroll") for (int _fm = 0; _fm < 4; ++_fm) \
  _Pragma("unroll") for (int _fn = 0; _fn < 2; ++_fn) { \
    acc[(MOFF)+_fm][(NOFF)+_fn] = __builtin_amdgcn_mfma_f32_16x16x32_f16(aF[_fm][0], BR[_fn][0], acc[(MOFF)+_fm][(NOFF)+_fn], 0, 0, 0); \
    acc[(MOFF)+_fm][(NOFF)+_fn] = __builtin_amdgcn_mfma_f32_16x16x32_f16(aF[_fm][1], BR[_fn][1], acc[(MOFF)+_fm][(NOFF)+_fn], 0, 0, 0); \
  } \
  __builtin_amdgcn_s_setprio(0); \
} while (0)

__global__ __launch_bounds__(512, 4) void gemm8(const half_t* __restrict__ A, int lda,
                                                const half_t* __restrict__ Bt,
                                                const float* __restrict__ bias,
                                                half_t* __restrict__ C, int ldc,
                                                const int* skip,
                                                float* __restrict__ qp) {
  if (skip && *skip == 0) return;
  extern __shared__ char smem[];
  const int t = threadIdx.x;
  const int ln = t & 63, wid = t >> 6;
  const int wm = wid >> 2, wn = wid & 3;

  const int gx = gridDim.x;
  const int nwg = gx * gridDim.y;
  const int orig = blockIdx.y * gx + blockIdx.x;
  const int swz = (orig & 7) * (nwg >> 3) + (orig >> 3);
  const int bx = swz % gx, by = swz / gx;
  const int n0 = bx * 256, m0 = by * 256;

  const int r8 = (t >> 3) & 7;
  const int grn = (t & 7) ^ r8;
  const int wbA = wid * 8;
  const int wbB = ((wid >> 2) << 6) + (wid & 3) * 8;
  const half_t* gA = A + (size_t)m0 * lda;
  const half_t* gB = Bt + (size_t)n0 * 1024;

  const int rA = (wm * 128 + (ln & 15)) * 128;
  const int rB = (wn * 64 + (ln & 15)) * 128;
  const int gsw0 = (((ln >> 4)) ^ (ln & 7)) << 4;
  const int gsw1 = ((4 | (ln >> 4)) ^ (ln & 7)) << 4;

  f32x4 acc[8][4] = {};
  f16x8 aF[4][2], bL[2][2], bH[2][2];

  // prologue: tile 0, all 4 halves; keep Aβ (last-issued 2) in flight
  SA2(0, 0); SB2(0, 0); SB2(32, 0); SA2(64, 0);
  WAITV(2); BARRIER();

#pragma unroll 1
  for (int kt = 0; kt < 16; ++kt) {
    const int kn = kt + 1;
    const bool f = (kt < 15);
    // ---- P1: read Aα(aLo) + Bγ(bL) + Bδ(bH); Q0
    LOAD_A(0); LOAD_B(bL, 0); LOAD_B(bH, 2);
    QUAD(bL, 0, 0); BARRIER();
    // ---- P2: stage Aα(kn),Bγ(kn); drain Aβ(kt) (keep newest 4); Q1
    if (f) { SA2(0, kn); SB2(0, kn); WAITV(4); } else WAITV(0);
    QUAD(bH, 0, 2); BARRIER();
    // ---- P3: read Aβ(aHi); stage Bδ(kn); Q2
    LOAD_A(4);
    if (f) SB2(32, kn);
    QUAD(bH, 4, 2); BARRIER();
    // ---- P4: stage Aβ(kn); drain Aα/Bγ/Bδ(kn) (keep newest 2); Q3
    if (f) { SA2(64, kn); WAITV(2); }
    QUAD(bL, 4, 0); BARRIER();
  }

  const int r0 = m0 + wm * 128 + ((ln >> 4) << 2);
  const int c0 = n0 + wn * 64 + (ln & 15);
  float bv4[4];
#pragma unroll
  for (int fn = 0; fn < 4; ++fn) bv4[fn] = bias[c0 + fn * 16];
#pragma unroll
  for (int fm = 0; fm < 8; ++fm)
#pragma unroll
    for (int fn = 0; fn < 4; ++fn) {
      const int col = c0 + fn * 16;
      const int row = r0 + fm * 16;
#pragma unroll
      for (int r = 0; r < 4; ++r)
        C[(size_t)(row + r) * ldc + col] = (half_t)(acc[fm][fn][r] + bv4[fn]);
    }

  if (qp && n0 < 1024) {
    const int bb = m0 >> 12;
    const int cb = ((m0 & 4095) >> 5) + wm * 4;
#pragma unroll
    for (int fn = 0; fn < 4; ++fn) {
#pragma unroll
      for (int j = 0; j < 4; ++j) {
        float s8 = bv4[fn] * 8.0f;
#pragma unroll
        for (int r = 0; r < 4; ++r) s8 += acc[2 * j][fn][r] + acc[2 * j + 1][fn][r];
        s8 += __shfl_xor(s8, 16, 64);
        s8 += __shfl_xor(s8, 32, 64);
        if (ln < 16)
          qp[((size_t)bb * NC + cb + j) * D_MODEL + c0 + fn * 16] = s8;
      }
    }
  }
}

// ================= row softmax (64 rows/block, nz path only) =================
__global__ __launch_bounds__(256) void softmax_k(const half_t* __restrict__ L,
                                                 half_t* __restrict__ O,
                                                 const int* skip) {
  if (*skip == 0) return;
  const int t = threadIdx.x;
  const int wv = t >> 6, ln = t & 63;
  __shared__ float sm[4], ssum[4];
#pragma unroll 1
  for (int i = 0; i < 64; ++i) {
    const size_t row = (size_t)blockIdx.x * 64 + i;
    f16x4 v = *(const f16x4*)(L + row * D_MODEL + t * 4);
    float x[4];
#pragma unroll
    for (int k = 0; k < 4; k++) x[k] = (float)v[k] * 0.03125f;
    float mx = fmaxf(fmaxf(x[0], x[1]), fmaxf(x[2], x[3]));
#pragma unroll
    for (int off = 32; off > 0; off >>= 1) mx = fmaxf(mx, __shfl_xor(mx, off, 64));
    if (ln == 0) sm[wv] = mx;
    __syncthreads();
    mx = fmaxf(fmaxf(sm[0], sm[1]), fmaxf(sm[2], sm[3]));
    float e[4]; float s = 0.f;
#pragma unroll
    for (int k = 0; k < 4; k++) { e[k] = expf(x[k] - mx); s += e[k]; }
#pragma unroll
    for (int off = 32; off > 0; off >>= 1) s += __shfl_xor(s, off, 64);
    if (ln == 0) ssum[wv] = s;
    __syncthreads();
    s = ssum[0] + ssum[1] + ssum[2] + ssum[3];
    const float r = 1.0f / s;
    f16x4 o;
#pragma unroll
    for (int k = 0; k < 4; k++) o[k] = (half_t)(e[k] * r);
    *(f16x4*)(O + row * D_MODEL + t * 4) = o;
    __syncthreads();
  }
}

// ================= cs_scan: (nz: compute partials) + exclusive chunk scan =================
__global__ __launch_bounds__(256) void cs_scan(const int* __restrict__ nz,
                                               float* __restrict__ pz,
                                               float* __restrict__ pn,
                                               const half_t* __restrict__ A, int ldA,
                                               const half_t* __restrict__ B, int ldB) {
  const int d = blockIdx.x * 256 + threadIdx.x;
  const int bb = blockIdx.y;
  if (*nz == 0) {
    float* p = pz + (size_t)bb * NC * D_MODEL + d;
    float acc = 0.f;
#pragma unroll 16
    for (int c = 0; c < NC; c++) {
      const float v = p[(size_t)c * D_MODEL];
      p[(size_t)c * D_MODEL] = acc;
      acc += v;
    }
  } else {
    float* p = pn + (size_t)bb * NC * D_MODEL + d;
    float acc = 0.f;
    for (int c = 0; c < NC; c++) {
      const size_t s0 = (size_t)bb * SEQ + (size_t)c * SC;
      float part = 0.f;
      for (int s = 0; s < SC; s++)
        part += (float)A[(s0 + s) * (size_t)ldA + d] * (float)B[(s0 + s) * (size_t)ldB + d];
      p[(size_t)c * D_MODEL] = acc;
      acc += part;
    }
  }
}

// ================= cumsum apply =================
template <bool HALF_OUT>
__global__ __launch_bounds__(256) void cs_apply(const int* __restrict__ nz,
                                                const float* __restrict__ wv,
                                                const half_t* __restrict__ A, int ldA,
                                                const half_t* __restrict__ B, int ldB,
                                                const half_t* __restrict__ Cm, int ldC,
                                                const float* __restrict__ pz,
                                                const float* __restrict__ pn,
                                                float* __restrict__ msum,
                                                half_t* __restrict__ OH,
                                                float* __restrict__ OF) {
  const int d = threadIdx.x * 4;
  const int c = blockIdx.y;
  const int bb = blockIdx.z;
  const size_t idx = ((size_t)bb * NC + c) * D_MODEL + d;
  const int nzv = *nz;
  f32x4 pr = *(const f32x4*)((nzv == 0 ? pz : pn) + idx);
  float acc[4] = {pr[0], pr[1], pr[2], pr[3]};
  const size_t s0 = (size_t)bb * SEQ + (size_t)c * SC;
  float ms[4] = {};
  if (nzv == 0) {
    f32x4 w = *(const f32x4*)&wv[d];
#pragma unroll 4
    for (int s = 0; s < SC; s++) {
      const size_t sg = s0 + s;
      f16x4 b = *(const f16x4*)&B[sg * ldB + d];
      f16x4 cm;
      if (HALF_OUT) cm = *(const f16x4*)&Cm[sg * ldC + d];
      else          cm = __builtin_nontemporal_load((const f16x4*)&Cm[sg * ldC + d]);
      const float rinv = 1.0f / (float)(c * SC + s + 1);
      float m[4];
#pragma unroll
      for (int j = 0; j < 4; j++) {
        acc[j] += (float)b[j];
        m[j] = w[j] * acc[j] * rinv * (float)cm[j];
        ms[j] += m[j];
      }
      if (HALF_OUT) {
        f16x4 o;
#pragma unroll
        for (int j = 0; j < 4; j++) o[j] = (half_t)m[j];
        *(f16x4*)&OH[sg * D_MODEL + d] = o;
      } else {
        __builtin_nontemporal_store(*(f32x4*)m, (f32x4*)&OF[sg * D_MODEL + d]);
      }
    }
  } else {
#pragma unroll 4
    for (int s = 0; s < SC; s++) {
      const size_t sg = s0 + s;
      f16x4 a = *(const f16x4*)&A[sg * ldA + d];
      f16x4 b = *(const f16x4*)&B[sg * ldB + d];
      f16x4 cm = *(const f16x4*)&Cm[sg * ldC + d];
      const float rinv = 1.0f / (float)(c * SC + s + 1);
      float m[4];
#pragma unroll
      for (int j = 0; j < 4; j++) {
        acc[j] += (float)a[j] * (float)b[j];
        m[j] = acc[j] * rinv * (float)cm[j];
        ms[j] += m[j];
      }
      if (HALF_OUT) {
        f16x4 o;
#pragma unroll
        for (int j = 0; j < 4; j++) o[j] = (half_t)m[j];
        *(f16x4*)&OH[sg * D_MODEL + d] = o;
      } else {
        __builtin_nontemporal_store(*(f32x4*)m, (f32x4*)&OF[sg * D_MODEL + d]);
      }
    }
  }
  if (msum) *(f32x4*)&msum[idx] = *(f32x4*)ms;
}

extern "C" void kernel_launch(void* const* d_in, const int* in_sizes, int n_in,
                              void* d_out, int out_size, void* d_ws, size_t ws_size,
                              hipStream_t stream) {
  const float* x     = (const float*)d_in[0];
  const float* Wq    = (const float*)d_in[2];
  const float* bq    = (const float*)d_in[3];
  const float* Wqa   = (const float*)d_in[4];
  const float* bqa   = (const float*)d_in[5];
  const float* Wk    = (const float*)d_in[6];
  const float* bk    = (const float*)d_in[7];
  const float* Wka   = (const float*)d_in[8];
  const float* bka   = (const float*)d_in[9];
  const float* Wv    = (const float*)d_in[10];
  const float* bv    = (const float*)d_in[11];
  const float* gamma = (const float*)d_in[12];
  const float* beta  = (const float*)d_in[13];
  float* out = (float*)d_out;

  char* ws = (char*)d_ws;
  const size_t MB = 1024 * 1024;
  half_t* h16    = (half_t*)(ws + 0);         // 32MB: h, reused as mixed16
  half_t* qkv16  = (half_t*)(ws + 32 * MB);   // 96MB
  half_t* logits = (half_t*)(ws + 128 * MB);  // 32MB (nz path only)
  half_t* wcat   = (half_t*)(ws + 160 * MB);  // 6MB (dead after gemm1)
  half_t* wqa16  = (half_t*)(ws + 166 * MB);  // 2MB
  half_t* wka16  = (half_t*)(ws + 168 * MB);  // 2MB
  float*  bcat   = (float*)(ws + 170 * MB);   // 12KB
  float*  pz1    = (float*)(ws + 128 * MB);          // 2MB (gemm1 chunk sums of q)
  float*  pn     = (float*)(ws + 160 * MB);          // 2MB (nz partials)
  float*  msum   = (float*)(ws + 162 * MB);          // 2MB (chunk sums of mixed)
  float*  qwv    = (float*)(ws + 170 * MB + 64 * 1024);  // 4KB
  float*  kwv    = (float*)(ws + 170 * MB + 68 * 1024);  // 4KB
  int*    flags  = (int*)(ws + 170 * MB + 72 * 1024);    // 8B
  unsigned* nzp  = (unsigned*)(ws + 170 * MB + 76 * 1024); // 2KB

  half_t* q16 = qkv16;            // ld 3072
  half_t* k16 = qkv16 + 1024;
  half_t* v16 = qkv16 + 2048;
  half_t* mixed16 = h16;
  half_t* sw = logits;

  hipFuncSetAttribute((const void*)gemm8, hipFuncAttributeMaxDynamicSharedMemorySize, 65536);

  setup1<<<22028, 256, 0, stream>>>(x, gamma, beta, h16, Wq, Wk, Wv, Wqa, Wka,
                                    wcat, wqa16, wka16, bq, bk, bv, bcat, nzp);
  setup2<<<2, 256, 0, stream>>>(nzp, flags, bqa, bka, qwv, kwv);
  // q|k|v = h @ [Wq|Wk|Wv] + b ; also emits chunk sums of q into pz1
  gemm8<<<dim3(12, 64), 512, 65536, stream>>>(h16, 1024, wcat, bcat, qkv16, 3072,
                                              nullptr, pz1);
  // logits = q @ Wqa + bqa  (skipped when Wqa == 0)
  gemm8<<<dim3(4, 64), 512, 65536, stream>>>(q16, 3072, wqa16, bqa, logits, 1024,
                                             flags, nullptr);
  softmax_k<<<256, 256, 0, stream>>>(logits, sw, flags);
  // scan stage 1: fast = scan pz1; nz = compute partials of sw.*q then scan
  cs_scan<<<dim3(4, BS), 256, 0, stream>>>(flags, pz1, pn, sw, 1024, q16, 3072);
  // mixed = (cumsum(qw.*q)/scale) .* k ; emits chunk sums of mixed into msum
  cs_apply<true><<<dim3(1, NC, BS), 256, 0, stream>>>(flags, qwv, sw, 1024, q16, 3072,
                                                      k16, 3072, pz1, pn, msum,
                                                      mixed16, nullptr);
  // logits = mixed @ Wka + bka  (skipped when Wka == 0)
  gemm8<<<dim3(4, 64), 512, 65536, stream>>>(mixed16, 1024, wka16, bka, logits, 1024,
                                             flags + 1, nullptr);
  softmax_k<<<256, 256, 0, stream>>>(logits, sw, flags + 1);
  // scan stage 2: fast = scan msum; nz = partials of sw.*mixed then scan
  cs_scan<<<dim3(4, BS), 256, 0, stream>>>(flags + 1, msum, pn, sw, 1024, mixed16, 1024);
  // out = (cumsum(kw.*mixed)/scale) .* v
  cs_apply<false><<<dim3(1, NC, BS), 256, 0, stream>>>(flags + 1, kwv, sw, 1024,
                                                       mixed16, 1024, v16, 3072,
                                                       msum, pn, nullptr, nullptr, out);
}

// Round 14
// 189.625 us; speedup vs baseline: 4.8653x; 4.8653x over previous
//
#include <hip/hip_runtime.h>

typedef _Float16 half_t;
typedef _Float16 f16x8 __attribute__((ext_vector_type(8)));
typedef _Float16 f16x4 __attribute__((ext_vector_type(4)));
typedef float f32x4 __attribute__((ext_vector_type(4)));

#define D_MODEL 1024
#define BS 4
#define SEQ 4096
#define ROWS (BS * SEQ)   // 16384
#define SC 32
#define NC (SEQ / SC)     // 128

#define BARRIER() asm volatile("s_barrier" ::: "memory")
#define WAITV(n)  asm volatile("s_waitcnt vmcnt(" #n ")" ::: "memory")

__device__ __forceinline__ void gld_lds16(const half_t* g, char* l) {
  __builtin_amdgcn_global_load_lds((const __attribute__((address_space(1))) void*)g,
                                   (__attribute__((address_space(3))) void*)l, 16, 0, 0);
}

// ================= setup1: ln + prep_w + detect_nz + copy_bias (fused) =================
__global__ __launch_bounds__(256) void setup1(const float* __restrict__ x,
                                              const float* __restrict__ gamma,
                                              const float* __restrict__ beta,
                                              half_t* __restrict__ h,
                                              const float* __restrict__ Wq,
                                              const float* __restrict__ Wk,
                                              const float* __restrict__ Wv,
                                              const float* __restrict__ Wqa,
                                              const float* __restrict__ Wka,
                                              half_t* __restrict__ wcat,
                                              half_t* __restrict__ wqa,
                                              half_t* __restrict__ wka,
                                              const float* __restrict__ bq,
                                              const float* __restrict__ bk,
                                              const float* __restrict__ bv,
                                              float* __restrict__ bcat,
                                              unsigned* __restrict__ nzpart) {
  __shared__ float sh[33 * 32];
  const int b = blockIdx.x;
  const int t = threadIdx.x;
  if (b < 16384) {
    // ---- layernorm row b (x is single-read: non-temporal) ----
    const float* xr = x + (size_t)b * D_MODEL + t * 4;
    f32x4 v = __builtin_nontemporal_load((const f32x4*)xr);
    float s = v[0] + v[1] + v[2] + v[3];
    float q = v[0]*v[0] + v[1]*v[1] + v[2]*v[2] + v[3]*v[3];
#pragma unroll
    for (int off = 32; off > 0; off >>= 1) {
      s += __shfl_down(s, off, 64);
      q += __shfl_down(q, off, 64);
    }
    const int wv = t >> 6, ln = t & 63;
    if (ln == 0) { sh[wv] = s; sh[4 + wv] = q; }
    __syncthreads();
    s = sh[0] + sh[1] + sh[2] + sh[3];
    q = sh[4] + sh[5] + sh[6] + sh[7];
    const float mu = s * (1.0f / D_MODEL);
    const float var = q * (1.0f / D_MODEL) - mu * mu;
    const float rstd = rsqrtf(var + 1e-5f);
    f32x4 g = *(const f32x4*)(gamma + t * 4);
    f32x4 bb = *(const f32x4*)(beta + t * 4);
    f16x4 o;
#pragma unroll
    for (int i = 0; i < 4; i++) o[i] = (half_t)((v[i] - mu) * rstd * g[i] + bb[i]);
    *(f16x4*)(h + (size_t)b * D_MODEL + t * 4) = o;
  } else if (b < 21504) {
    const int bi = b - 16384;
    const int mat = bi >> 10;
    const int tile = bi & 1023;
    const int tn = (tile & 31) * 32;
    const int tk = (tile >> 5) * 32;
    const float* W = mat == 0 ? Wq : mat == 1 ? Wk : mat == 2 ? Wv : mat == 3 ? Wqa : Wka;
    half_t* dst = mat < 3 ? wcat + (size_t)mat * D_MODEL * D_MODEL : (mat == 3 ? wqa : wka);
    float (*tl)[33] = (float(*)[33])sh;
    const int tx = t & 31, ty = t >> 5;
#pragma unroll
    for (int i = 0; i < 32; i += 8)
      tl[ty + i][tx] = W[(size_t)(tk + ty + i) * D_MODEL + tn + tx];
    __syncthreads();
#pragma unroll
    for (int i = 0; i < 32; i += 8)
      dst[(size_t)(tn + ty + i) * D_MODEL + tk + tx] = (half_t)tl[tx][ty + i];
  } else if (b < 22016) {
    const int bi = b - 21504;
    const int which = bi >> 8;
    const unsigned* w = (const unsigned*)(which ? Wka : Wqa);
    const int blk = bi & 255;
    unsigned v = 0;
    const size_t base = (size_t)blk * 4096 + t;
#pragma unroll
    for (int i = 0; i < 16; ++i) v |= w[base + i * 256];
#pragma unroll
    for (int off = 32; off > 0; off >>= 1) v |= __shfl_down(v, off, 64);
    unsigned* sv = (unsigned*)sh;
    if ((t & 63) == 0) sv[t >> 6] = v;
    __syncthreads();
    if (t == 0) nzpart[bi] = sv[0] | sv[1] | sv[2] | sv[3];
  } else {
    const int i = (b - 22016) * 256 + t;
    if (i < 1024) bcat[i] = bq[i];
    else if (i < 2048) bcat[i] = bk[i - 1024];
    else if (i < 3072) bcat[i] = bv[i - 2048];
  }
}

// ================= setup2: flag reduce + bias softmax (2 blocks) =================
__global__ __launch_bounds__(256) void setup2(const unsigned* __restrict__ nzpart,
                                              int* __restrict__ flags,
                                              const float* __restrict__ bqa,
                                              const float* __restrict__ bka,
                                              float* __restrict__ qwv,
                                              float* __restrict__ kwv) {
  const int b = blockIdx.x;
  const int t = threadIdx.x;
  __shared__ float sm[4], ssum[4];
  __shared__ unsigned su[4];
  unsigned u = nzpart[b * 256 + t];
#pragma unroll
  for (int off = 32; off > 0; off >>= 1) u |= __shfl_down(u, off, 64);
  const int wv = t >> 6, ln = t & 63;
  if (ln == 0) su[wv] = u;
  __syncthreads();
  if (t == 0) flags[b] = (su[0] | su[1] | su[2] | su[3]) ? 1 : 0;
  const float* bb = b ? bka : bqa;
  float* o = b ? kwv : qwv;
  f32x4 v = *(const f32x4*)(bb + t * 4);
  float xv[4];
#pragma unroll
  for (int i = 0; i < 4; i++) xv[i] = v[i] * 0.03125f;
  float mx = fmaxf(fmaxf(xv[0], xv[1]), fmaxf(xv[2], xv[3]));
#pragma unroll
  for (int off = 32; off > 0; off >>= 1) mx = fmaxf(mx, __shfl_xor(mx, off, 64));
  if (ln == 0) sm[wv] = mx;
  __syncthreads();
  mx = fmaxf(fmaxf(sm[0], sm[1]), fmaxf(sm[2], sm[3]));
  float e[4]; float s = 0.f;
#pragma unroll
  for (int i = 0; i < 4; i++) { e[i] = expf(xv[i] - mx); s += e[i]; }
#pragma unroll
  for (int off = 32; off > 0; off >>= 1) s += __shfl_xor(s, off, 64);
  if (ln == 0) ssum[wv] = s;
  __syncthreads();
  s = ssum[0] + ssum[1] + ssum[2] + ssum[3];
  const float r = 1.0f / s;
  f32x4 ov;
#pragma unroll
  for (int i = 0; i < 4; i++) ov[i] = e[i] * r;
  *(f32x4*)(o + t * 4) = ov;
}

// ================= 256x256 8-phase MFMA GEMM (16x16x32), K=1024 (frozen) =================

#define SA2(buf, rb, kt) do { \
  gld_lds16(gA + (size_t)((rb) + wbA + r8) * lda + (size_t)(kt) * 64 + grn * 8, \
            smem + (buf)*65536 + ((rb) + wbA) * 128); \
  gld_lds16(gA + (size_t)((rb) + 128 + wbA + r8) * lda + (size_t)(kt) * 64 + grn * 8, \
            smem + (buf)*65536 + ((rb) + 128 + wbA) * 128); \
} while (0)

#define SB2(buf, gd, kt) do { \
  gld_lds16(gB + (size_t)((gd) + wbB + r8) * 1024 + (size_t)(kt) * 64 + grn * 8, \
            smem + (buf)*65536 + 32768 + ((gd) + wbB) * 128); \
  gld_lds16(gB + (size_t)((gd) + 128 + wbB + r8) * 1024 + (size_t)(kt) * 64 + grn * 8, \
            smem + (buf)*65536 + 32768 + ((gd) + 128 + wbB) * 128); \
} while (0)

#define LOAD_A(buf, base) do { \
  _Pragma("unroll") for (int _fm = 0; _fm < 4; ++_fm) { \
    aF[_fm][0] = *(const f16x8*)(smem + (buf)*65536 + rA + gsw0 + ((base)+_fm)*2048); \
    aF[_fm][1] = *(const f16x8*)(smem + (buf)*65536 + rA + gsw1 + ((base)+_fm)*2048); \
  } \
} while (0)

#define LOAD_B(dst, buf, base) do { \
  _Pragma("unroll") for (int _fn = 0; _fn < 2; ++_fn) { \
    dst[_fn][0] = *(const f16x8*)(smem + (buf)*65536 + 32768 + rB + gsw0 + ((base)+_fn)*2048); \
    dst[_fn][1] = *(const f16x8*)(smem + (buf)*65536 + 32768 + rB + gsw1 + ((base)+_fn)*2048); \
  } \
} while (0)

#define QUAD(BR, MOFF, NOFF) do { \
  __builtin_amdgcn_s_setprio(1); \
  _Pragma("unroll") for (int _fm = 0; _fm < 4; ++_fm) \
  _Pragma("unroll") for (int _fn = 0; _fn < 2; ++_fn) { \
    acc[(MOFF)+_fm][(NOFF)+_fn] = __builtin_amdgcn_mfma_f32_16x16x32_f16(aF[_fm][0], BR[_fn][0], acc[(MOFF)+_fm][(NOFF)+_fn], 0, 0, 0); \
    acc[(MOFF)+_fm][(NOFF)+_fn] = __builtin_amdgcn_mfma_f32_16x16x32_f16(aF[_fm][1], BR[_fn][1], acc[(MOFF)+_fm][(NOFF)+_fn], 0, 0, 0); \
  } \
  __builtin_amdgcn_s_setprio(0); \
} while (0)

__global__ __launch_bounds__(512, 2) void gemm8(const half_t* __restrict__ A, int lda,
                                                const half_t* __restrict__ Bt,
                                                const float* __restrict__ bias,
                                                half_t* __restrict__ C, int ldc,
                                                const int* skip,
                                                float* __restrict__ qp) {
  if (skip && *skip == 0) return;
  extern __shared__ char smem[];
  const int t = threadIdx.x;
  const int ln = t & 63, wid = t >> 6;
  const int wm = wid >> 2, wn = wid & 3;

  const int gx = gridDim.x;
  const int nwg = gx * gridDim.y;
  const int orig = blockIdx.y * gx + blockIdx.x;
  const int swz = (orig & 7) * (nwg >> 3) + (orig >> 3);
  const int bx = swz % gx, by = swz / gx;
  const int n0 = bx * 256, m0 = by * 256;

  const int r8 = (t >> 3) & 7;
  const int grn = (t & 7) ^ r8;
  const int wbA = wid * 8;
  const int wbB = ((wid >> 2) << 6) + (wid & 3) * 8;
  const half_t* gA = A + (size_t)m0 * lda;
  const half_t* gB = Bt + (size_t)n0 * 1024;

  const int rA = (wm * 128 + (ln & 15)) * 128;
  const int rB = (wn * 64 + (ln & 15)) * 128;
  const int gsw0 = (((ln >> 4)) ^ (ln & 7)) << 4;
  const int gsw1 = ((4 | (ln >> 4)) ^ (ln & 7)) << 4;

  f32x4 acc[8][4] = {};
  f16x8 aF[4][2], bL[2][2], bH[2][2];

  SA2(0, 0, 0); SB2(0, 0, 0); SA2(0, 64, 0); SB2(0, 32, 0);
  SA2(1, 0, 1); SB2(1, 0, 1); SA2(1, 64, 1);
  WAITV(6); BARRIER();

#pragma unroll 1
  for (int i = 0; i < 8; ++i) {
    const int kb = 2 * i + 1;
    const int kc = 2 * i + 2;
    const int kd = 2 * i + 3;
    const bool f = (i < 7);
    LOAD_A(0, 0); LOAD_B(bL, 0, 0); LOAD_B(bH, 0, 2);
    SB2(1, 32, kb);
    QUAD(bL, 0, 0); BARRIER();
    if (f) SA2(0, 0, kc);
    QUAD(bH, 0, 2); BARRIER();
    LOAD_A(0, 4);
    if (f) SB2(0, 0, kc);
    QUAD(bH, 4, 2); BARRIER();
    if (f) { SA2(0, 64, kc); WAITV(6); } else WAITV(0);
    QUAD(bL, 4, 0); BARRIER();
    LOAD_A(1, 0); LOAD_B(bL, 1, 0); LOAD_B(bH, 1, 2);
    if (f) SB2(0, 32, kc);
    QUAD(bL, 0, 0); BARRIER();
    if (f) SA2(1, 0, kd);
    QUAD(bH, 0, 2); BARRIER();
    LOAD_A(1, 4);
    if (f) SB2(1, 0, kd);
    QUAD(bH, 4, 2); BARRIER();
    if (f) { SA2(1, 64, kd); WAITV(6); }
    QUAD(bL, 4, 0); BARRIER();
  }

  const int r0 = m0 + wm * 128 + ((ln >> 4) << 2);
  const int c0 = n0 + wn * 64 + (ln & 15);
  float bv4[4];
#pragma unroll
  for (int fn = 0; fn < 4; ++fn) bv4[fn] = bias[c0 + fn * 16];
#pragma unroll
  for (int fm = 0; fm < 8; ++fm)
#pragma unroll
    for (int fn = 0; fn < 4; ++fn) {
      const int col = c0 + fn * 16;
      const int row = r0 + fm * 16;
#pragma unroll
      for (int r = 0; r < 4; ++r)
        C[(size_t)(row + r) * ldc + col] = (half_t)(acc[fm][fn][r] + bv4[fn]);
    }

  if (qp && n0 < 1024) {
    const int bb = m0 >> 12;
    const int cb = ((m0 & 4095) >> 5) + wm * 4;
#pragma unroll
    for (int fn = 0; fn < 4; ++fn) {
#pragma unroll
      for (int j = 0; j < 4; ++j) {
        float s8 = bv4[fn] * 8.0f;
#pragma unroll
        for (int r = 0; r < 4; ++r) s8 += acc[2 * j][fn][r] + acc[2 * j + 1][fn][r];
        s8 += __shfl_xor(s8, 16, 64);
        s8 += __shfl_xor(s8, 32, 64);
        if (ln < 16)
          qp[((size_t)bb * NC + cb + j) * D_MODEL + c0 + fn * 16] = s8;
      }
    }
  }
}

// ================= row softmax (64 rows/block, nz path only) =================
__global__ __launch_bounds__(256) void softmax_k(const half_t* __restrict__ L,
                                                 half_t* __restrict__ O,
                                                 const int* skip) {
  if (*skip == 0) return;
  const int t = threadIdx.x;
  const int wv = t >> 6, ln = t & 63;
  __shared__ float sm[4], ssum[4];
#pragma unroll 1
  for (int i = 0; i < 64; ++i) {
    const size_t row = (size_t)blockIdx.x * 64 + i;
    f16x4 v = *(const f16x4*)(L + row * D_MODEL + t * 4);
    float x[4];
#pragma unroll
    for (int k = 0; k < 4; k++) x[k] = (float)v[k] * 0.03125f;
    float mx = fmaxf(fmaxf(x[0], x[1]), fmaxf(x[2], x[3]));
#pragma unroll
    for (int off = 32; off > 0; off >>= 1) mx = fmaxf(mx, __shfl_xor(mx, off, 64));
    if (ln == 0) sm[wv] = mx;
    __syncthreads();
    mx = fmaxf(fmaxf(sm[0], sm[1]), fmaxf(sm[2], sm[3]));
    float e[4]; float s = 0.f;
#pragma unroll
    for (int k = 0; k < 4; k++) { e[k] = expf(x[k] - mx); s += e[k]; }
#pragma unroll
    for (int off = 32; off > 0; off >>= 1) s += __shfl_xor(s, off, 64);
    if (ln == 0) ssum[wv] = s;
    __syncthreads();
    s = ssum[0] + ssum[1] + ssum[2] + ssum[3];
    const float r = 1.0f / s;
    f16x4 o;
#pragma unroll
    for (int k = 0; k < 4; k++) o[k] = (half_t)(e[k] * r);
    *(f16x4*)(O + row * D_MODEL + t * 4) = o;
    __syncthreads();
  }
}

// ================= cs_scan: (nz: compute partials) + exclusive chunk scan =================
__global__ __launch_bounds__(256) void cs_scan(const int* __restrict__ nz,
                                               float* __restrict__ pz,
                                               float* __restrict__ pn,
                                               const half_t* __restrict__ A, int ldA,
                                               const half_t* __restrict__ B, int ldB) {
  const int d = blockIdx.x * 256 + threadIdx.x;
  const int bb = blockIdx.y;
  if (*nz == 0) {
    float* p = pz + (size_t)bb * NC * D_MODEL + d;
    float acc = 0.f;
#pragma unroll 16
    for (int c = 0; c < NC; c++) {
      const float v = p[(size_t)c * D_MODEL];
      p[(size_t)c * D_MODEL] = acc;
      acc += v;
    }
  } else {
    float* p = pn + (size_t)bb * NC * D_MODEL + d;
    float acc = 0.f;
    for (int c = 0; c < NC; c++) {
      const size_t s0 = (size_t)bb * SEQ + (size_t)c * SC;
      float part = 0.f;
      for (int s = 0; s < SC; s++)
        part += (float)A[(s0 + s) * (size_t)ldA + d] * (float)B[(s0 + s) * (size_t)ldB + d];
      p[(size_t)c * D_MODEL] = acc;
      acc += part;
    }
  }
}

// ================= cumsum apply =================
template <bool HALF_OUT>
__global__ __launch_bounds__(256) void cs_apply(const int* __restrict__ nz,
                                                const float* __restrict__ wv,
                                                const half_t* __restrict__ A, int ldA,
                                                const half_t* __restrict__ B, int ldB,
                                                const half_t* __restrict__ Cm, int ldC,
                                                const float* __restrict__ pz,
                                                const float* __restrict__ pn,
                                                float* __restrict__ msum,
                                                half_t* __restrict__ OH,
                                                float* __restrict__ OF) {
  const int d = threadIdx.x * 4;
  const int c = blockIdx.y;
  const int bb = blockIdx.z;
  const size_t idx = ((size_t)bb * NC + c) * D_MODEL + d;
  const int nzv = *nz;
  f32x4 pr = *(const f32x4*)((nzv == 0 ? pz : pn) + idx);
  float acc[4] = {pr[0], pr[1], pr[2], pr[3]};
  const size_t s0 = (size_t)bb * SEQ + (size_t)c * SC;
  float ms[4] = {};
  if (nzv == 0) {
    f32x4 w = *(const f32x4*)&wv[d];
#pragma unroll 4
    for (int s = 0; s < SC; s++) {
      const size_t sg = s0 + s;
      f16x4 b = *(const f16x4*)&B[sg * ldB + d];
      f16x4 cm;
      if (HALF_OUT) cm = *(const f16x4*)&Cm[sg * ldC + d];
      else          cm = __builtin_nontemporal_load((const f16x4*)&Cm[sg * ldC + d]);
      const float rinv = 1.0f / (float)(c * SC + s + 1);
      float m[4];
#pragma unroll
      for (int j = 0; j < 4; j++) {
        acc[j] += (float)b[j];
        m[j] = w[j] * acc[j] * rinv * (float)cm[j];
        ms[j] += m[j];
      }
      if (HALF_OUT) {
        f16x4 o;
#pragma unroll
        for (int j = 0; j < 4; j++) o[j] = (half_t)m[j];
        *(f16x4*)&OH[sg * D_MODEL + d] = o;
      } else {
        __builtin_nontemporal_store(*(f32x4*)m, (f32x4*)&OF[sg * D_MODEL + d]);
      }
    }
  } else {
#pragma unroll 4
    for (int s = 0; s < SC; s++) {
      const size_t sg = s0 + s;
      f16x4 a = *(const f16x4*)&A[sg * ldA + d];
      f16x4 b = *(const f16x4*)&B[sg * ldB + d];
      f16x4 cm = *(const f16x4*)&Cm[sg * ldC + d];
      const float rinv = 1.0f / (float)(c * SC + s + 1);
      float m[4];
#pragma unroll
      for (int j = 0; j < 4; j++) {
        acc[j] += (float)a[j] * (float)b[j];
        m[j] = acc[j] * rinv * (float)cm[j];
        ms[j] += m[j];
      }
      if (HALF_OUT) {
        f16x4 o;
#pragma unroll
        for (int j = 0; j < 4; j++) o[j] = (half_t)m[j];
        *(f16x4*)&OH[sg * D_MODEL + d] = o;
      } else {
        __builtin_nontemporal_store(*(f32x4*)m, (f32x4*)&OF[sg * D_MODEL + d]);
      }
    }
  }
  if (msum) *(f32x4*)&msum[idx] = *(f32x4*)ms;
}

extern "C" void kernel_launch(void* const* d_in, const int* in_sizes, int n_in,
                              void* d_out, int out_size, void* d_ws, size_t ws_size,
                              hipStream_t stream) {
  const float* x     = (const float*)d_in[0];
  const float* Wq    = (const float*)d_in[2];
  const float* bq    = (const float*)d_in[3];
  const float* Wqa   = (const float*)d_in[4];
  const float* bqa   = (const float*)d_in[5];
  const float* Wk    = (const float*)d_in[6];
  const float* bk    = (const float*)d_in[7];
  const float* Wka   = (const float*)d_in[8];
  const float* bka   = (const float*)d_in[9];
  const float* Wv    = (const float*)d_in[10];
  const float* bv    = (const float*)d_in[11];
  const float* gamma = (const float*)d_in[12];
  const float* beta  = (const float*)d_in[13];
  float* out = (float*)d_out;

  char* ws = (char*)d_ws;
  const size_t MB = 1024 * 1024;
  half_t* h16    = (half_t*)(ws + 0);         // 32MB: h, reused as mixed16
  half_t* qkv16  = (half_t*)(ws + 32 * MB);   // 96MB
  half_t* logits = (half_t*)(ws + 128 * MB);  // 32MB (nz path only)
  half_t* wcat   = (half_t*)(ws + 160 * MB);  // 6MB (dead after gemm1)
  half_t* wqa16  = (half_t*)(ws + 166 * MB);  // 2MB
  half_t* wka16  = (half_t*)(ws + 168 * MB);  // 2MB
  float*  bcat   = (float*)(ws + 170 * MB);   // 12KB
  float*  pz1    = (float*)(ws + 128 * MB);          // 2MB (gemm1 chunk sums of q)
  float*  pn     = (float*)(ws + 160 * MB);          // 2MB (nz partials)
  float*  msum   = (float*)(ws + 162 * MB);          // 2MB (chunk sums of mixed)
  float*  qwv    = (float*)(ws + 170 * MB + 64 * 1024);  // 4KB
  float*  kwv    = (float*)(ws + 170 * MB + 68 * 1024);  // 4KB
  int*    flags  = (int*)(ws + 170 * MB + 72 * 1024);    // 8B
  unsigned* nzp  = (unsigned*)(ws + 170 * MB + 76 * 1024); // 2KB

  half_t* q16 = qkv16;            // ld 3072
  half_t* k16 = qkv16 + 1024;
  half_t* v16 = qkv16 + 2048;
  half_t* mixed16 = h16;
  half_t* sw = logits;

  hipFuncSetAttribute((const void*)gemm8, hipFuncAttributeMaxDynamicSharedMemorySize, 131072);

  setup1<<<22028, 256, 0, stream>>>(x, gamma, beta, h16, Wq, Wk, Wv, Wqa, Wka,
                                    wcat, wqa16, wka16, bq, bk, bv, bcat, nzp);
  setup2<<<2, 256, 0, stream>>>(nzp, flags, bqa, bka, qwv, kwv);
  // q|k|v = h @ [Wq|Wk|Wv] + b ; also emits chunk sums of q into pz1
  gemm8<<<dim3(12, 64), 512, 131072, stream>>>(h16, 1024, wcat, bcat, qkv16, 3072,
                                               nullptr, pz1);
  // logits = q @ Wqa + bqa  (skipped when Wqa == 0)
  gemm8<<<dim3(4, 64), 512, 131072, stream>>>(q16, 3072, wqa16, bqa, logits, 1024,
                                              flags, nullptr);
  softmax_k<<<256, 256, 0, stream>>>(logits, sw, flags);
  // scan stage 1: fast = scan pz1; nz = compute partials of sw.*q then scan
  cs_scan<<<dim3(4, BS), 256, 0, stream>>>(flags, pz1, pn, sw, 1024, q16, 3072);
  // mixed = (cumsum(qw.*q)/scale) .* k ; emits chunk sums of mixed into msum
  cs_apply<true><<<dim3(1, NC, BS), 256, 0, stream>>>(flags, qwv, sw, 1024, q16, 3072,
                                                      k16, 3072, pz1, pn, msum,
                                                      mixed16, nullptr);
  // logits = mixed @ Wka + bka  (skipped when Wka == 0)
  gemm8<<<dim3(4, 64), 512, 131072, stream>>>(mixed16, 1024, wka16, bka, logits, 1024,
                                              flags + 1, nullptr);
  softmax_k<<<256, 256, 0, stream>>>(logits, sw, flags + 1);
  // scan stage 2: fast = scan msum; nz = partials of sw.*mixed then scan
  cs_scan<<<dim3(4, BS), 256, 0, stream>>>(flags + 1, msum, pn, sw, 1024, mixed16, 1024);
  // out = (cumsum(kw.*mixed)/scale) .* v
  cs_apply<false><<<dim3(1, NC, BS), 256, 0, stream>>>(flags + 1, kwv, sw, 1024,
                                                       mixed16, 1024, v16, 3072,
                                                       msum, pn, nullptr, nullptr, out);
}